// Round 1
// baseline (122.083 us; speedup 1.0000x reference)
//
#include <hip/hip_runtime.h>

// Problem constants (from reference): B=16, C=1, H=768, W=768, K=512
#define BDIM 16
#define HDIM 768
#define WDIM 768
#define KCOR 512
constexpr int HW = HDIM * WDIM;          // 589824
constexpr int TOTAL = BDIM * HW;         // 9437184
constexpr int TOTALQ = TOTAL / 4;        // 2359296 float4 quads

// ---------------------------------------------------------------------------
// Kernel 1: streaming pass over all elements.
// Computes acc = sum over elements of (peak + (gt>0?5:1)) * (pre-gt)^2
// peak = strict 4-neighbor maximum with zero padding at image borders.
// The gt-scatter XOR correction is applied by corr_kernel.
// ---------------------------------------------------------------------------
__global__ __launch_bounds__(256) void main_kernel(
    const float* __restrict__ pre,
    const float* __restrict__ gt,
    float* __restrict__ out) {

    float acc = 0.0f;
    const int nthreads = gridDim.x * blockDim.x;
    for (int q = blockIdx.x * blockDim.x + threadIdx.x; q < TOTALQ; q += nthreads) {
        const int idx = q * 4;                 // global flat element index (16B aligned)
        const int rem = idx % HW;              // position within one image
        const int row = rem / WDIM;
        const int x   = rem % WDIM;

        const float4 c4 = *(const float4*)(pre + idx);
        const float4 g4 = *(const float4*)(gt + idx);
        const float  lft = (x > 0)          ? pre[idx - 1] : 0.0f;
        const float  rgt = (x + 4 < WDIM)   ? pre[idx + 4] : 0.0f;
        const float4 u4 = (row > 0)         ? *(const float4*)(pre + idx - WDIM)
                                            : make_float4(0.f, 0.f, 0.f, 0.f);
        const float4 d4 = (row < HDIM - 1)  ? *(const float4*)(pre + idx + WDIM)
                                            : make_float4(0.f, 0.f, 0.f, 0.f);

        const float c[4]  = {c4.x, c4.y, c4.z, c4.w};
        const float g[4]  = {g4.x, g4.y, g4.z, g4.w};
        const float u[4]  = {u4.x, u4.y, u4.z, u4.w};
        const float d[4]  = {d4.x, d4.y, d4.z, d4.w};
        const float lr[6] = {lft, c[0], c[1], c[2], c[3], rgt};

        #pragma unroll
        for (int j = 0; j < 4; ++j) {
            const bool peak = (c[j] > lr[j]) && (c[j] > lr[j + 2]) &&
                              (c[j] > u[j]) && (c[j] > d[j]);
            float e = c[j] - g[j];
            e *= e;
            const float wt = (g[j] > 0.0f ? 5.0f : 1.0f) + (peak ? 1.0f : 0.0f);
            acc += wt * e;
        }
    }

    // wave (64-lane) reduction
    #pragma unroll
    for (int off = 32; off > 0; off >>= 1) acc += __shfl_down(acc, off);

    __shared__ float lds[4];                   // 256 threads = 4 waves
    const int wave = threadIdx.x >> 6;
    const int lane = threadIdx.x & 63;
    if (lane == 0) lds[wave] = acc;
    __syncthreads();
    if (threadIdx.x == 0) {
        const float s = lds[0] + lds[1] + lds[2] + lds[3];
        atomicAdd(out, s * (1.0f / (float)BDIM));
    }
}

// ---------------------------------------------------------------------------
// Kernel 2: gt-coordinate correction.
// At each UNIQUE gt position: mask1 = !peak instead of peak, so the
// correction vs. kernel 1's base sum is (1 - 2*peak) * err.
// Duplicate coordinates (the reference scatter is a set) are deduped by an
// O(K^2) LDS scan — only the first occurrence contributes.
// ---------------------------------------------------------------------------
__global__ __launch_bounds__(KCOR) void corr_kernel(
    const float* __restrict__ pre,
    const float* __restrict__ gt,
    const int* __restrict__ cors,   // (B, K, 2) as [x, y]
    float* __restrict__ out) {

    __shared__ int scoord[KCOR];
    const int b = blockIdx.x;
    const int k = threadIdx.x;
    const int x = cors[(b * KCOR + k) * 2 + 0];
    const int y = cors[(b * KCOR + k) * 2 + 1];
    const int packed = y * WDIM + x;
    scoord[k] = packed;
    __syncthreads();

    bool dup = false;
    for (int k2 = 0; k2 < k; ++k2) dup |= (scoord[k2] == packed);

    float contrib = 0.0f;
    if (!dup) {
        const int idx = b * HW + packed;
        const float c = pre[idx];
        const float l = (x > 0)        ? pre[idx - 1]    : 0.0f;
        const float r = (x < WDIM - 1) ? pre[idx + 1]    : 0.0f;
        const float u = (y > 0)        ? pre[idx - WDIM] : 0.0f;
        const float d = (y < HDIM - 1) ? pre[idx + WDIM] : 0.0f;
        const bool peak = (c > l) && (c > r) && (c > u) && (c > d);
        float e = c - gt[idx];
        e *= e;
        contrib = (peak ? -1.0f : 1.0f) * e;
    }

    #pragma unroll
    for (int off = 32; off > 0; off >>= 1) contrib += __shfl_down(contrib, off);

    __shared__ float lds[8];                   // 512 threads = 8 waves
    const int wave = threadIdx.x >> 6;
    const int lane = threadIdx.x & 63;
    if (lane == 0) lds[wave] = contrib;
    __syncthreads();
    if (threadIdx.x == 0) {
        float s = 0.0f;
        #pragma unroll
        for (int i = 0; i < 8; ++i) s += lds[i];
        atomicAdd(out, s * (1.0f / (float)BDIM));
    }
}

extern "C" void kernel_launch(void* const* d_in, const int* in_sizes, int n_in,
                              void* d_out, int out_size, void* d_ws, size_t ws_size,
                              hipStream_t stream) {
    const float* pre  = (const float*)d_in[0];   // (16,1,768,768) fp32
    const float* gt   = (const float*)d_in[1];   // (16,1,768,768) fp32
    const int*   cors = (const int*)d_in[2];     // (16,512,2) int32

    float* out = (float*)d_out;                  // single fp32 scalar

    // d_out is poisoned to 0xAA before every timed launch — zero it.
    hipMemsetAsync(out, 0, sizeof(float), stream);

    // Streaming pass: 1024 blocks x 256 threads, 9 float4-quads per thread.
    main_kernel<<<1024, 256, 0, stream>>>(pre, gt, out);

    // Correction pass: one block per batch image.
    corr_kernel<<<BDIM, KCOR, 0, stream>>>(pre, gt, cors, out);
}